// Round 1
// baseline (602.251 us; speedup 1.0000x reference)
//
#include <hip/hip_runtime.h>

#define D 128
#define TWO_D 256
#define EDIM 16
#define BN_EPS 1e-3f

// ---------------------------------------------------------------------------
// Kernel 1: fold the two edge-encoder dense layers (linear . linear = linear)
//   Wf[k][d] = sum_j We1[k][j] * We2[j][d]      (16 x 128)
//   bf[d]    = sum_j be1[j]   * We2[j][d] + be2[d]
// ---------------------------------------------------------------------------
__global__ __launch_bounds__(256)
void fold_edge_weights(const float* __restrict__ We1,  // [16][256]
                       const float* __restrict__ be1,  // [256]
                       const float* __restrict__ We2,  // [256][128]
                       const float* __restrict__ be2,  // [128]
                       float* __restrict__ Wf,         // [16][128]
                       float* __restrict__ bf)         // [128]
{
    int tid = blockIdx.x * blockDim.x + threadIdx.x;
    if (tid < EDIM * D) {
        int k = tid / D, d = tid % D;
        float acc = 0.f;
        for (int j = 0; j < TWO_D; ++j)
            acc += We1[k * TWO_D + j] * We2[j * D + d];
        Wf[tid] = acc;
    } else if (tid < EDIM * D + D) {
        int d = tid - EDIM * D;
        float acc = be2[d];
        for (int j = 0; j < TWO_D; ++j)
            acc += be1[j] * We2[j * D + d];
        bf[d] = acc;
    }
}

// ---------------------------------------------------------------------------
// Kernel 2: per-edge: e = ef @ Wf + bf ; msg = relu(e + node_feat[src]) ;
//           atomic scatter-add msg into pooled[dst]  (pooled aliased to d_out)
// One wave per edge (grid-stride). Folded weights live in registers.
// ---------------------------------------------------------------------------
__global__ __launch_bounds__(256)
void edge_scatter(const float* __restrict__ edge_feat,  // [E][16]
                  const int*   __restrict__ src,
                  const int*   __restrict__ dst,
                  const float* __restrict__ node_feat,  // [N][128]
                  const float* __restrict__ Wf,         // [16][128]
                  const float* __restrict__ bf,         // [128]
                  float* __restrict__ pooled,           // [N][128]
                  int n_edges)
{
    const int lane    = threadIdx.x & 63;
    const int wave    = blockIdx.x * (blockDim.x >> 6) + (threadIdx.x >> 6);
    const int n_waves = gridDim.x * (blockDim.x >> 6);

    // Folded edge weights: 32 VGPRs per lane, loaded once per wave.
    float wf0[EDIM], wf1[EDIM];
#pragma unroll
    for (int k = 0; k < EDIM; ++k) {
        wf0[k] = Wf[k * D + lane];
        wf1[k] = Wf[k * D + lane + 64];
    }
    const float bf0 = bf[lane], bf1 = bf[lane + 64];

    for (int e = wave; e < n_edges; e += n_waves) {
        const int s = src[e];
        const int t = dst[e];
        const float4* ef4 = (const float4*)(edge_feat + (size_t)e * EDIM);
        float4 f0 = ef4[0], f1 = ef4[1], f2 = ef4[2], f3 = ef4[3];
        float ef[EDIM] = {f0.x, f0.y, f0.z, f0.w,
                          f1.x, f1.y, f1.z, f1.w,
                          f2.x, f2.y, f2.z, f2.w,
                          f3.x, f3.y, f3.z, f3.w};
        float a0 = bf0, a1 = bf1;
#pragma unroll
        for (int k = 0; k < EDIM; ++k) {
            a0 = fmaf(ef[k], wf0[k], a0);
            a1 = fmaf(ef[k], wf1[k], a1);
        }
        a0 += node_feat[(size_t)s * D + lane];
        a1 += node_feat[(size_t)s * D + lane + 64];
        a0 = fmaxf(a0, 0.f);
        a1 = fmaxf(a1, 0.f);
        unsafeAtomicAdd(&pooled[(size_t)t * D + lane],      a0);
        unsafeAtomicAdd(&pooled[(size_t)t * D + lane + 64], a1);
    }
}

// ---------------------------------------------------------------------------
// Kernel 3: per-node GIN MLP with both BatchNorms folded to affine:
//   h   = (1+eps)*node_feat + pooled            (pooled read from d_out)
//   t   = relu((h @ Wm1) * s1 + t1)             s1 = g1*rsqrt(v1+eps)
//   out = (t @ Wm2) * s2 + t2                   t1 = (bm1-m1)*s1 + b1  etc.
// 16-node tile per 256-thread block; h/t staged in LDS, float4 LDS reads.
// Block b reads pooled rows [16b,16b+16) and later writes the same rows: safe.
// ---------------------------------------------------------------------------
#define NT 16
__global__ __launch_bounds__(256)
void node_mlp(const float* __restrict__ node_feat,  // [N][128]
              const float* __restrict__ eps,        // [1]
              const float* __restrict__ Wm1,        // [128][256]
              const float* __restrict__ bm1,        // [256]
              const float* __restrict__ g1,
              const float* __restrict__ b1,
              const float* __restrict__ m1,
              const float* __restrict__ v1,
              const float* __restrict__ Wm2,        // [256][128]
              const float* __restrict__ bm2,        // [128]
              const float* __restrict__ g2,
              const float* __restrict__ b2,
              const float* __restrict__ m2,
              const float* __restrict__ v2,
              float* __restrict__ out)              // [N][128], also pooled in
{
    __shared__ float hbuf[NT * D];      // 8 KB
    __shared__ float tbuf[NT * TWO_D];  // 16 KB

    const int tid = threadIdx.x;
    const int n0  = blockIdx.x * NT;
    const float ep = 1.0f + eps[0];

    // ---- load h tile (fully coalesced: rows are consecutive) ----
    for (int i = tid; i < NT * D; i += 256) {
        size_t gi = (size_t)n0 * D + i;
        hbuf[i] = ep * node_feat[gi] + out[gi];
    }
    __syncthreads();

    // ---- layer 1: thread owns column c for all 16 nodes ----
    const int c = tid;
    float acc[NT];
#pragma unroll
    for (int n = 0; n < NT; ++n) acc[n] = 0.f;

    for (int k0 = 0; k0 < D; k0 += 4) {
        const float w0 = Wm1[(k0 + 0) * TWO_D + c];
        const float w1 = Wm1[(k0 + 1) * TWO_D + c];
        const float w2 = Wm1[(k0 + 2) * TWO_D + c];
        const float w3 = Wm1[(k0 + 3) * TWO_D + c];
#pragma unroll
        for (int n = 0; n < NT; ++n) {
            float4 h4 = *(const float4*)&hbuf[n * D + k0];
            acc[n] = fmaf(h4.x, w0, acc[n]);
            acc[n] = fmaf(h4.y, w1, acc[n]);
            acc[n] = fmaf(h4.z, w2, acc[n]);
            acc[n] = fmaf(h4.w, w3, acc[n]);
        }
    }
    const float s1 = g1[c] * rsqrtf(v1[c] + BN_EPS);
    const float t1 = (bm1[c] - m1[c]) * s1 + b1[c];
#pragma unroll
    for (int n = 0; n < NT; ++n)
        tbuf[n * TWO_D + c] = fmaxf(fmaf(acc[n], s1, t1), 0.f);
    __syncthreads();

    // ---- layer 2: half-block g owns nodes [8g, 8g+8), thread column d ----
    const int d = tid & (D - 1);
    const int g = tid >> 7;  // 0 or 1
    float acc2[NT / 2];
#pragma unroll
    for (int n = 0; n < NT / 2; ++n) acc2[n] = 0.f;

    for (int k0 = 0; k0 < TWO_D; k0 += 4) {
        const float w0 = Wm2[(k0 + 0) * D + d];
        const float w1 = Wm2[(k0 + 1) * D + d];
        const float w2 = Wm2[(k0 + 2) * D + d];
        const float w3 = Wm2[(k0 + 3) * D + d];
#pragma unroll
        for (int n = 0; n < NT / 2; ++n) {
            float4 t4 = *(const float4*)&tbuf[(g * (NT / 2) + n) * TWO_D + k0];
            acc2[n] = fmaf(t4.x, w0, acc2[n]);
            acc2[n] = fmaf(t4.y, w1, acc2[n]);
            acc2[n] = fmaf(t4.z, w2, acc2[n]);
            acc2[n] = fmaf(t4.w, w3, acc2[n]);
        }
    }
    const float s2 = g2[d] * rsqrtf(v2[d] + BN_EPS);
    const float t2 = (bm2[d] - m2[d]) * s2 + b2[d];
#pragma unroll
    for (int n = 0; n < NT / 2; ++n) {
        int nn = n0 + g * (NT / 2) + n;
        out[(size_t)nn * D + d] = fmaf(acc2[n], s2, t2);
    }
}

// ---------------------------------------------------------------------------
extern "C" void kernel_launch(void* const* d_in, const int* in_sizes, int n_in,
                              void* d_out, int out_size, void* d_ws, size_t ws_size,
                              hipStream_t stream) {
    const float* node_feat = (const float*)d_in[0];
    const float* edge_feat = (const float*)d_in[1];
    const int*   src       = (const int*)d_in[2];
    const int*   dst       = (const int*)d_in[3];
    const float* We1       = (const float*)d_in[4];
    const float* be1       = (const float*)d_in[5];
    const float* We2       = (const float*)d_in[6];
    const float* be2       = (const float*)d_in[7];
    const float* eps       = (const float*)d_in[8];
    const float* Wm1       = (const float*)d_in[9];
    const float* bm1       = (const float*)d_in[10];
    const float* g1        = (const float*)d_in[11];
    const float* b1        = (const float*)d_in[12];
    const float* m1        = (const float*)d_in[13];
    const float* v1        = (const float*)d_in[14];
    const float* Wm2       = (const float*)d_in[15];
    const float* bm2       = (const float*)d_in[16];
    const float* g2        = (const float*)d_in[17];
    const float* b2        = (const float*)d_in[18];
    const float* m2        = (const float*)d_in[19];
    const float* v2        = (const float*)d_in[20];

    const int n_nodes = in_sizes[0] / D;
    const int n_edges = in_sizes[2];

    float* Wf = (float*)d_ws;           // 16*128 floats
    float* bf = Wf + EDIM * D;          // 128 floats

    float* out = (float*)d_out;

    // pooled accumulator lives in d_out; zero it (harness poisons with 0xAA)
    hipMemsetAsync(d_out, 0, (size_t)out_size * sizeof(float), stream);

    // fold edge-encoder weights
    fold_edge_weights<<<(EDIM * D + D + 255) / 256, 256, 0, stream>>>(
        We1, be1, We2, be2, Wf, bf);

    // edge gather/compute/scatter
    edge_scatter<<<4096, 256, 0, stream>>>(
        edge_feat, src, dst, node_feat, Wf, bf, out, n_edges);

    // node MLP (reads pooled from out, overwrites out)
    node_mlp<<<n_nodes / NT, 256, 0, stream>>>(
        node_feat, eps, Wm1, bm1, g1, b1, m1, v1,
        Wm2, bm2, g2, b2, m2, v2, out);
}